// Round 4
// baseline (1792.239 us; speedup 1.0000x reference)
//
#include <hip/hip_runtime.h>

#define C_IN   32
#define C_OUT  32
#define K_VOL  27
#define M_EDGE 250000
#define N_ROWS 500000
#define E_TOT  (K_VOL * M_EDGE)          // 6,750,000 edges

#define BUCKET_BITS 8
#define BUCKET_SZ   (1 << BUCKET_BITS)   // 256 output rows per bucket
#define NBUCK       ((N_ROWS + BUCKET_SZ - 1) / BUCKET_SZ)  // 1954
#define NBINS       (K_VOL * NBUCK)      // 52,758 (bin = k*NBUCK + bucket)
#define LDS_STRIDE  33
#define NSCAN_BLK   ((NBINS + 1023) / 1024)   // 52

typedef __attribute__((ext_vector_type(8))) short s16x8;   // 8 bf16
typedef __attribute__((ext_vector_type(4))) float f32x4;

// round-to-nearest-even fp32 -> bf16
static __device__ __forceinline__ unsigned short f2bf(float x) {
    union { float f; unsigned int u; } c; c.f = x;
    const unsigned int r = (c.u + 0x7FFFu + ((c.u >> 16) & 1u)) >> 16;
    return (unsigned short)r;
}

// ---------------- Prep: feats fp32 -> bf16 (8 elems/thread) ----------------
__global__ __launch_bounds__(256) void cvt_feats(
    const float* __restrict__ f, unsigned short* __restrict__ o)
{
    const int i = blockIdx.x * 256 + threadIdx.x;
    if (i >= N_ROWS * C_IN / 8) return;
    const float4 v0 = reinterpret_cast<const float4*>(f)[i * 2];
    const float4 v1 = reinterpret_cast<const float4*>(f)[i * 2 + 1];
    s16x8 r;
    r[0] = (short)f2bf(v0.x); r[1] = (short)f2bf(v0.y);
    r[2] = (short)f2bf(v0.z); r[3] = (short)f2bf(v0.w);
    r[4] = (short)f2bf(v1.x); r[5] = (short)f2bf(v1.y);
    r[6] = (short)f2bf(v1.z); r[7] = (short)f2bf(v1.w);
    *reinterpret_cast<s16x8*>(o + (size_t)i * 8) = r;
}

// ---------------- Prep: weight fp32 [k][ci][co] -> bf16 transposed [k][co][ci] ----------------
__global__ __launch_bounds__(256) void cvt_w(
    const float* __restrict__ w, unsigned short* __restrict__ wT)
{
    const int idx = blockIdx.x * 256 + threadIdx.x;
    if (idx >= K_VOL * C_IN * C_OUT) return;
    const int k = idx >> 10, rem = idx & 1023;
    const int co = rem >> 5, ci = rem & 31;
    wT[idx] = f2bf(w[k * 1024 + ci * 32 + co]);
}

// ---------------- Phase A: histogram (4 edges/thread via int4) ----------------
__global__ __launch_bounds__(256) void hist_kernel(
    const int* __restrict__ out_idx, int* __restrict__ counts)
{
    const int k  = blockIdx.y;
    const int m4 = blockIdx.x * 256 + threadIdx.x;
    if (m4 >= M_EDGE / 4) return;
    const int4 r = reinterpret_cast<const int4*>(out_idx + k * M_EDGE)[m4];
    int* cb = counts + k * NBUCK;
    atomicAdd(&cb[r.x >> BUCKET_BITS], 1);
    atomicAdd(&cb[r.y >> BUCKET_BITS], 1);
    atomicAdd(&cb[r.z >> BUCKET_BITS], 1);
    atomicAdd(&cb[r.w >> BUCKET_BITS], 1);
}

// ---------------- Phase B: two-level exclusive scan ----------------
__global__ __launch_bounds__(1024) void scan1_kernel(
    const int* __restrict__ counts, int* __restrict__ offsets,
    int* __restrict__ bsum)
{
    __shared__ int buf[1024];
    const int tid = threadIdx.x;
    const int i = blockIdx.x * 1024 + tid;
    const int v = (i < NBINS) ? counts[i] : 0;
    buf[tid] = v;
    __syncthreads();
    for (int off = 1; off < 1024; off <<= 1) {
        const int t = (tid >= off) ? buf[tid - off] : 0;
        __syncthreads();
        buf[tid] += t;
        __syncthreads();
    }
    if (i < NBINS) offsets[i] = buf[tid] - v;        // block-local exclusive
    if (tid == 1023) bsum[blockIdx.x] = buf[1023];
}

__global__ void scan2_kernel(int* __restrict__ bsum)
{
    if (threadIdx.x == 0) {
        int run = 0;
        for (int b = 0; b < NSCAN_BLK; ++b) { const int t = bsum[b]; bsum[b] = run; run += t; }
    }
}

__global__ __launch_bounds__(1024) void scan3_kernel(
    int* __restrict__ offsets, const int* __restrict__ bsum,
    int* __restrict__ cursors)
{
    const int i = blockIdx.x * 1024 + threadIdx.x;
    if (i < NBINS) {
        const int o = offsets[i] + bsum[blockIdx.x];
        offsets[i] = o;
        cursors[i] = o;
    }
    if (i == 0) offsets[NBINS] = E_TOT;
}

// ---------------- Phase C: scatter payloads (4 edges/thread) ----------------
// payload: in_row (19 bits) | local_out_row (8 bits) << 19; k implicit in bin.
__global__ __launch_bounds__(256) void fill_kernel(
    const int* __restrict__ in_idx, const int* __restrict__ out_idx,
    int* __restrict__ cursors, unsigned int* __restrict__ edge_buf)
{
    const int k  = blockIdx.y;
    const int m4 = blockIdx.x * 256 + threadIdx.x;
    if (m4 >= M_EDGE / 4) return;
    const int4 ro = reinterpret_cast<const int4*>(out_idx + k * M_EDGE)[m4];
    const int4 ri = reinterpret_cast<const int4*>(in_idx  + k * M_EDGE)[m4];
    int* cb = cursors + k * NBUCK;
    const int rows[4]  = {ro.x, ro.y, ro.z, ro.w};
    const int irows[4] = {ri.x, ri.y, ri.z, ri.w};
#pragma unroll
    for (int j = 0; j < 4; ++j) {
        const int row = rows[j];
        const int pos = atomicAdd(&cb[row >> BUCKET_BITS], 1);
        edge_buf[pos] = (unsigned int)irows[j] |
                        ((unsigned int)(row & (BUCKET_SZ - 1)) << 19);
    }
}

// ---------------- Phase D: per-bucket MFMA conv ----------------
// 4 waves/block. Per 16-edge tile: 1 payload load (broadcast), 1 A-frag gather
// (lane = slot x chunk, zero redundancy), 2 MFMA (co halves), 4 shuffles, 8
// LDS atomics into the bucket accumulator. Weights = 8 VGPRs per k per half.
__global__ __launch_bounds__(256) void conv_mfma(
    const unsigned short* __restrict__ feats16,
    const unsigned short* __restrict__ wT16,
    const int* __restrict__ offsets,
    const unsigned int* __restrict__ edge_buf,
    float* __restrict__ out)
{
    __shared__ float acc[BUCKET_SZ * LDS_STRIDE];   // 33.8 KB
    const int bucket = blockIdx.x;
    const int tid = threadIdx.x;
    for (int i = tid; i < BUCKET_SZ * LDS_STRIDE; i += 256) acc[i] = 0.f;
    __syncthreads();

    const int lane  = tid & 63;
    const int wv    = tid >> 6;    // wave 0..3
    const int slot  = lane & 15;   // edge slot in tile (A row / D col-index use)
    const int chunk = lane >> 4;   // 8-channel chunk 0..3

#pragma unroll 1
    for (int k = 0; k < K_VOL; ++k) {
        const unsigned short* wk = wT16 + k * (C_IN * C_OUT);
        // B-fragments: lane holds wT[k][co=slot(+16)][ci=chunk*8..+7]
        const s16x8 b0 = *reinterpret_cast<const s16x8*>(wk + slot * 32 + chunk * 8);
        const s16x8 b1 = *reinterpret_cast<const s16x8*>(wk + (slot + 16) * 32 + chunk * 8);

        const int bin = k * NBUCK + bucket;
        const int s = offsets[bin], e = offsets[bin + 1];
#pragma unroll 1
        for (int t = s + wv * 16; t < e; t += 64) {
            const int idx = t + slot;
            const bool valid = idx < e;
            unsigned int p = 0u;
            if (valid) p = edge_buf[idx];            // 16 addrs, 4-way broadcast
            const int irow = (int)(p & 0x7FFFFu);
            const int lrow = (int)(p >> 19);
            s16x8 a = {0, 0, 0, 0, 0, 0, 0, 0};
            if (valid)                                // invalid slots: A row = 0
                a = *reinterpret_cast<const s16x8*>(
                        feats16 + (size_t)irow * C_IN + chunk * 8);
            const f32x4 z = {0.f, 0.f, 0.f, 0.f};
            f32x4 c0 = __builtin_amdgcn_mfma_f32_16x16x32_bf16(a, b0, z, 0, 0, 0);
            f32x4 c1 = __builtin_amdgcn_mfma_f32_16x16x32_bf16(a, b1, z, 0, 0, 0);
            // D layout: col(co)=lane&15, row(edge slot)=chunk*4+j
#pragma unroll
            for (int j = 0; j < 4; ++j) {
                const int lr = __shfl(lrow, chunk * 4 + j, 64);
                unsafeAtomicAdd(&acc[lr * LDS_STRIDE + slot],      c0[j]);
                unsafeAtomicAdd(&acc[lr * LDS_STRIDE + 16 + slot], c1[j]);
            }
        }
    }
    __syncthreads();

    const int row0 = bucket << BUCKET_BITS;
    const int nrows = min(BUCKET_SZ, N_ROWS - row0);
    for (int i = tid; i < nrows * 8; i += 256) {          // 8 float4 per row
        const int r = i >> 3, c = (i & 7) * 4;
        const float4 v = make_float4(acc[r * LDS_STRIDE + c],
                                     acc[r * LDS_STRIDE + c + 1],
                                     acc[r * LDS_STRIDE + c + 2],
                                     acc[r * LDS_STRIDE + c + 3]);
        *reinterpret_cast<float4*>(out + (size_t)(row0 + r) * C_OUT + c) = v;
    }
}

// ---------------- Fallback (edge-atomic) if ws too small ----------------
__global__ __launch_bounds__(256) void spconv_edges(
    const float* __restrict__ feats, const float* __restrict__ weight,
    const int* __restrict__ in_idx, const int* __restrict__ out_idx,
    float* __restrict__ out)
{
    const int k = blockIdx.y;
    const int tid = threadIdx.x;
    const int g = tid >> 3, l = tid & 7, c0 = l * 4;
    const float* wk = weight + k * (C_IN * C_OUT);
    float4 wr[32];
#pragma unroll
    for (int ci = 0; ci < 32; ++ci)
        wr[ci] = *reinterpret_cast<const float4*>(wk + ci * C_OUT + c0);
    const int* ik = in_idx + k * M_EDGE;
    const int* ok = out_idx + k * M_EDGE;
    int m = blockIdx.x * 1024 + g;
#pragma unroll 1
    for (int it = 0; it < 32; ++it, m += 32) {
        if (m >= M_EDGE) break;
        const int irow = ik[m], orow = ok[m];
        const float4* frow =
            reinterpret_cast<const float4*>(feats + (size_t)irow * C_IN);
        float4 a = make_float4(0.f, 0.f, 0.f, 0.f);
#pragma unroll
        for (int j = 0; j < 8; ++j) {
            const float4 f4 = frow[j];
            const float fv[4] = {f4.x, f4.y, f4.z, f4.w};
#pragma unroll
            for (int t = 0; t < 4; ++t) {
                const float4 w4 = wr[j * 4 + t];
                a.x = fmaf(fv[t], w4.x, a.x);
                a.y = fmaf(fv[t], w4.y, a.y);
                a.z = fmaf(fv[t], w4.z, a.z);
                a.w = fmaf(fv[t], w4.w, a.w);
            }
        }
        float* op = out + (size_t)orow * C_OUT + c0;
        unsafeAtomicAdd(op + 0, a.x);
        unsafeAtomicAdd(op + 1, a.y);
        unsafeAtomicAdd(op + 2, a.z);
        unsafeAtomicAdd(op + 3, a.w);
    }
}

extern "C" void kernel_launch(void* const* d_in, const int* in_sizes, int n_in,
                              void* d_out, int out_size, void* d_ws, size_t ws_size,
                              hipStream_t stream) {
    const float* feats   = (const float*)d_in[0];
    const float* weight  = (const float*)d_in[1];
    const int*   in_idx  = (const int*)d_in[2];
    const int*   out_idx = (const int*)d_in[3];
    float*       out     = (float*)d_out;

    // workspace layout (all 64-B aligned by construction)
    const size_t feats16_elems = (size_t)N_ROWS * C_IN;            // 16M ushort
    const size_t wT16_elems    = (size_t)K_VOL * C_IN * C_OUT;     // 27,648
    const size_t ints_after    = (size_t)(3 * NBINS + 1 + NSCAN_BLK);
    const size_t need_bytes = feats16_elems * 2 + wT16_elems * 2 +
                              ints_after * sizeof(int) + (size_t)E_TOT * 4 + 256;

    if (ws_size >= need_bytes) {
        unsigned short* feats16 = (unsigned short*)d_ws;
        unsigned short* wT16    = feats16 + feats16_elems;
        int* counts  = (int*)(wT16 + wT16_elems);
        int* offsets = counts + NBINS;            // NBINS+1
        int* cursors = offsets + NBINS + 1;       // NBINS
        int* bsum    = cursors + NBINS;           // NSCAN_BLK
        unsigned int* edge_buf = (unsigned int*)(bsum + NSCAN_BLK);  // E_TOT

        hipMemsetAsync(counts, 0, NBINS * sizeof(int), stream);
        cvt_feats<<<(N_ROWS * C_IN / 8 + 255) / 256, 256, 0, stream>>>(feats, feats16);
        cvt_w<<<(K_VOL * C_IN * C_OUT + 255) / 256, 256, 0, stream>>>(weight, wT16);

        dim3 gEdges4((M_EDGE / 4 + 255) / 256, K_VOL);
        hist_kernel<<<gEdges4, 256, 0, stream>>>(out_idx, counts);
        scan1_kernel<<<NSCAN_BLK, 1024, 0, stream>>>(counts, offsets, bsum);
        scan2_kernel<<<1, 64, 0, stream>>>(bsum);
        scan3_kernel<<<NSCAN_BLK, 1024, 0, stream>>>(offsets, bsum, cursors);
        fill_kernel<<<gEdges4, 256, 0, stream>>>(in_idx, out_idx, cursors, edge_buf);
        conv_mfma<<<NBUCK, 256, 0, stream>>>(feats16, wT16, offsets, edge_buf, out);
    } else {
        hipMemsetAsync(out, 0, (size_t)out_size * sizeof(float), stream);
        dim3 grid((M_EDGE + 1023) / 1024, K_VOL);
        spconv_edges<<<grid, dim3(256), 0, stream>>>(feats, weight, in_idx, out_idx, out);
    }
}

// Round 5
// 1193.697 us; speedup vs baseline: 1.5014x; 1.5014x over previous
//
#include <hip/hip_runtime.h>

#define C_IN   32
#define C_OUT  32
#define K_VOL  27
#define M_EDGE 250000
#define N_ROWS 500000
#define E_TOT  (K_VOL * M_EDGE)          // 6,750,000 edges

#define NT     (N_ROWS / 16)             // 31250 row-tiles of 16 rows (exact)
#define NBINS  (NT * K_VOL)              // 843,750  (bin = rt*27 + k)
#define NSCAN_BLK ((NBINS + 1023) / 1024) // 824

typedef __attribute__((ext_vector_type(8))) short s16x8;   // 8 bf16
typedef __attribute__((ext_vector_type(4))) float f32x4;

// fp32 -> bf16 round-to-nearest-even
static __device__ __forceinline__ unsigned short f2bf(float x) {
    union { float f; unsigned int u; } c; c.f = x;
    const unsigned int r = (c.u + 0x7FFFu + ((c.u >> 16) & 1u)) >> 16;
    return (unsigned short)r;
}
// bf16 -> fp32 (exact)
static __device__ __forceinline__ float bf2f(unsigned short s) {
    union { unsigned int u; float f; } c; c.u = ((unsigned int)s) << 16;
    return c.f;
}

// ---------------- Prep: feats fp32 -> bf16 ----------------
__global__ __launch_bounds__(256) void cvt_feats(
    const float* __restrict__ f, unsigned short* __restrict__ o)
{
    const int i = blockIdx.x * 256 + threadIdx.x;
    if (i >= N_ROWS * C_IN / 8) return;
    const float4 v0 = reinterpret_cast<const float4*>(f)[i * 2];
    const float4 v1 = reinterpret_cast<const float4*>(f)[i * 2 + 1];
    s16x8 r;
    r[0] = (short)f2bf(v0.x); r[1] = (short)f2bf(v0.y);
    r[2] = (short)f2bf(v0.z); r[3] = (short)f2bf(v0.w);
    r[4] = (short)f2bf(v1.x); r[5] = (short)f2bf(v1.y);
    r[6] = (short)f2bf(v1.z); r[7] = (short)f2bf(v1.w);
    *reinterpret_cast<s16x8*>(o + (size_t)i * 8) = r;
}

// ---------------- Prep: weight fp32 [k][ci][co] -> bf16 [k][co][ci] ----------------
__global__ __launch_bounds__(256) void cvt_w(
    const float* __restrict__ w, unsigned short* __restrict__ wT)
{
    const int idx = blockIdx.x * 256 + threadIdx.x;
    if (idx >= K_VOL * C_IN * C_OUT) return;
    const int k = idx >> 10, rem = idx & 1023;
    const int co = rem >> 5, ci = rem & 31;
    wT[idx] = f2bf(w[k * 1024 + ci * 32 + co]);
}

// ---------------- Phase A: histogram over (row-tile, k) bins ----------------
__global__ __launch_bounds__(256) void hist_kernel(
    const int* __restrict__ out_idx, int* __restrict__ counts)
{
    const int k  = blockIdx.y;
    const int m4 = blockIdx.x * 256 + threadIdx.x;
    if (m4 >= M_EDGE / 4) return;
    const int4 r = reinterpret_cast<const int4*>(out_idx + k * M_EDGE)[m4];
    atomicAdd(&counts[(r.x >> 4) * K_VOL + k], 1);
    atomicAdd(&counts[(r.y >> 4) * K_VOL + k], 1);
    atomicAdd(&counts[(r.z >> 4) * K_VOL + k], 1);
    atomicAdd(&counts[(r.w >> 4) * K_VOL + k], 1);
}

// ---------------- Phase B: two-level exclusive scan over NBINS ----------------
__global__ __launch_bounds__(1024) void scan1_kernel(
    const int* __restrict__ counts, int* __restrict__ offsets,
    int* __restrict__ bsum)
{
    __shared__ int buf[1024];
    const int tid = threadIdx.x;
    const int i = blockIdx.x * 1024 + tid;
    const int v = (i < NBINS) ? counts[i] : 0;
    buf[tid] = v;
    __syncthreads();
    for (int off = 1; off < 1024; off <<= 1) {
        const int t = (tid >= off) ? buf[tid - off] : 0;
        __syncthreads();
        buf[tid] += t;
        __syncthreads();
    }
    if (i < NBINS) offsets[i] = buf[tid] - v;        // block-local exclusive
    if (tid == 1023) bsum[blockIdx.x] = buf[1023];
}

__global__ __launch_bounds__(1024) void scan2_kernel(int* __restrict__ bsum)
{
    __shared__ int buf[1024];
    const int tid = threadIdx.x;
    const int v = (tid < NSCAN_BLK) ? bsum[tid] : 0;
    buf[tid] = v;
    __syncthreads();
    for (int off = 1; off < 1024; off <<= 1) {
        const int t = (tid >= off) ? buf[tid - off] : 0;
        __syncthreads();
        buf[tid] += t;
        __syncthreads();
    }
    if (tid < NSCAN_BLK) bsum[tid] = buf[tid] - v;   // exclusive
}

__global__ __launch_bounds__(1024) void scan3_kernel(
    int* __restrict__ offsets, const int* __restrict__ bsum,
    int* __restrict__ cursors)
{
    const int i = blockIdx.x * 1024 + threadIdx.x;
    if (i < NBINS) {
        const int o = offsets[i] + bsum[blockIdx.x];
        offsets[i] = o;
        cursors[i] = o;
    }
    if (i == 0) offsets[NBINS] = E_TOT;
}

// ---------------- Phase C: scatter payloads into bin segments ----------------
// payload: in_row (19 bits) | local_row-in-tile (4 bits) << 19; bits >=23 zero.
__global__ __launch_bounds__(256) void fill_kernel(
    const int* __restrict__ in_idx, const int* __restrict__ out_idx,
    int* __restrict__ cursors, unsigned int* __restrict__ edge_buf)
{
    const int k  = blockIdx.y;
    const int m4 = blockIdx.x * 256 + threadIdx.x;
    if (m4 >= M_EDGE / 4) return;
    const int4 ro = reinterpret_cast<const int4*>(out_idx + k * M_EDGE)[m4];
    const int4 ri = reinterpret_cast<const int4*>(in_idx  + k * M_EDGE)[m4];
    const int rows[4]  = {ro.x, ro.y, ro.z, ro.w};
    const int irows[4] = {ri.x, ri.y, ri.z, ri.w};
#pragma unroll
    for (int j = 0; j < 4; ++j) {
        const int row = rows[j];
        const int pos = atomicAdd(&cursors[(row >> 4) * K_VOL + k], 1);
        edge_buf[pos] = (unsigned int)irows[j] |
                        ((unsigned int)(row & 15) << 19);
    }
}

// ---------------- Phase D: register-accumulated MFMA conv (ZERO atomics) ----------------
// One wave per 16-row output tile. Per k: build A[r][ci] = sum of gathered
// feats rows (f32 accumulate in regs), 2 MFMAs accumulate C across all 27 k
// in VGPRs. Output stored once, coalesced. No LDS at all.
__global__ __launch_bounds__(256) void conv_mfma2(
    const unsigned short* __restrict__ feats16,
    const unsigned short* __restrict__ wT16,
    const int* __restrict__ offsets,
    const unsigned int* __restrict__ edge_buf,
    float* __restrict__ out)
{
    const int tid  = threadIdx.x;
    const int lane = tid & 63;
    const int wid  = tid >> 6;
    const int rt   = blockIdx.x * 4 + wid;     // row-tile this wave owns
    if (rt >= NT) return;                       // wave-uniform exit
    const int slot  = lane & 15;                // output row within tile / co col
    const int chunk = lane >> 4;                // 8-channel ci chunk

    // prefetch the 28 offsets for this tile's 27 bins (contiguous: bin=rt*27+k)
    const int base = rt * K_VOL;
    const int myoff = (lane < K_VOL + 1) ? offsets[base + lane] : 0;

    f32x4 c0 = {0.f, 0.f, 0.f, 0.f};
    f32x4 c1 = {0.f, 0.f, 0.f, 0.f};

#pragma unroll 1
    for (int k = 0; k < K_VOL; ++k) {
        int s       = __builtin_amdgcn_readlane(myoff, k);
        const int e = __builtin_amdgcn_readlane(myoff, k + 1);
        if (s == e) continue;

        float af[8] = {0.f, 0.f, 0.f, 0.f, 0.f, 0.f, 0.f, 0.f};
        while (s < e) {
            const int batch = min(64, e - s);
            // 64-wide parallel payload load; sentinel bit 23 never matches a slot
            const unsigned int pv =
                (lane < batch) ? edge_buf[s + lane] : 0x00800000u;
#pragma unroll 1
            for (int jj = 0; jj < batch; jj += 4) {
                const unsigned int p0 = __builtin_amdgcn_readlane(pv, jj);
                const unsigned int p1 = __builtin_amdgcn_readlane(pv, jj + 1);
                const unsigned int p2 = __builtin_amdgcn_readlane(pv, jj + 2);
                const unsigned int p3 = __builtin_amdgcn_readlane(pv, jj + 3);
                s16x8 f0 = {0,0,0,0,0,0,0,0}, f1 = {0,0,0,0,0,0,0,0};
                s16x8 f2 = {0,0,0,0,0,0,0,0}, f3 = {0,0,0,0,0,0,0,0};
                // 4 independent masked gathers -> 4 loads in flight
                if (((p0 >> 19) & 31u) == (unsigned)slot)
                    f0 = *reinterpret_cast<const s16x8*>(
                        feats16 + ((size_t)(p0 & 0x7FFFFu)) * C_IN + chunk * 8);
                if (((p1 >> 19) & 31u) == (unsigned)slot)
                    f1 = *reinterpret_cast<const s16x8*>(
                        feats16 + ((size_t)(p1 & 0x7FFFFu)) * C_IN + chunk * 8);
                if (((p2 >> 19) & 31u) == (unsigned)slot)
                    f2 = *reinterpret_cast<const s16x8*>(
                        feats16 + ((size_t)(p2 & 0x7FFFFu)) * C_IN + chunk * 8);
                if (((p3 >> 19) & 31u) == (unsigned)slot)
                    f3 = *reinterpret_cast<const s16x8*>(
                        feats16 + ((size_t)(p3 & 0x7FFFFu)) * C_IN + chunk * 8);
#pragma unroll
                for (int q = 0; q < 8; ++q)
                    af[q] += (bf2f((unsigned short)f0[q]) + bf2f((unsigned short)f1[q])) +
                             (bf2f((unsigned short)f2[q]) + bf2f((unsigned short)f3[q]));
            }
            s += batch;
        }

        s16x8 a;
#pragma unroll
        for (int q = 0; q < 8; ++q) a[q] = (short)f2bf(af[q]);

        const unsigned short* wk = wT16 + k * (C_IN * C_OUT);
        const s16x8 b0 = *reinterpret_cast<const s16x8*>(wk + slot * 32 + chunk * 8);
        const s16x8 b1 = *reinterpret_cast<const s16x8*>(wk + (slot + 16) * 32 + chunk * 8);
        c0 = __builtin_amdgcn_mfma_f32_16x16x32_bf16(a, b0, c0, 0, 0, 0);
        c1 = __builtin_amdgcn_mfma_f32_16x16x32_bf16(a, b1, c1, 0, 0, 0);
    }

    // D layout: col(co)=lane&15, row=(lane>>4)*4+j  -> out row = rt*16+chunk*4+j
    const int r0 = rt * 16 + chunk * 4;
#pragma unroll
    for (int j = 0; j < 4; ++j) {
        out[(size_t)(r0 + j) * C_OUT + slot]      = c0[j];
        out[(size_t)(r0 + j) * C_OUT + 16 + slot] = c1[j];
    }
}

// ---------------- Fallback (edge-atomic) if ws too small ----------------
__global__ __launch_bounds__(256) void spconv_edges(
    const float* __restrict__ feats, const float* __restrict__ weight,
    const int* __restrict__ in_idx, const int* __restrict__ out_idx,
    float* __restrict__ out)
{
    const int k = blockIdx.y;
    const int tid = threadIdx.x;
    const int g = tid >> 3, l = tid & 7, c0 = l * 4;
    const float* wk = weight + k * (C_IN * C_OUT);
    float4 wr[32];
#pragma unroll
    for (int ci = 0; ci < 32; ++ci)
        wr[ci] = *reinterpret_cast<const float4*>(wk + ci * C_OUT + c0);
    const int* ik = in_idx + k * M_EDGE;
    const int* ok = out_idx + k * M_EDGE;
    int m = blockIdx.x * 1024 + g;
#pragma unroll 1
    for (int it = 0; it < 32; ++it, m += 32) {
        if (m >= M_EDGE) break;
        const int irow = ik[m], orow = ok[m];
        const float4* frow =
            reinterpret_cast<const float4*>(feats + (size_t)irow * C_IN);
        float4 a = make_float4(0.f, 0.f, 0.f, 0.f);
#pragma unroll
        for (int j = 0; j < 8; ++j) {
            const float4 f4 = frow[j];
            const float fv[4] = {f4.x, f4.y, f4.z, f4.w};
#pragma unroll
            for (int t = 0; t < 4; ++t) {
                const float4 w4 = wr[j * 4 + t];
                a.x = fmaf(fv[t], w4.x, a.x);
                a.y = fmaf(fv[t], w4.y, a.y);
                a.z = fmaf(fv[t], w4.z, a.z);
                a.w = fmaf(fv[t], w4.w, a.w);
            }
        }
        float* op = out + (size_t)orow * C_OUT + c0;
        unsafeAtomicAdd(op + 0, a.x);
        unsafeAtomicAdd(op + 1, a.y);
        unsafeAtomicAdd(op + 2, a.z);
        unsafeAtomicAdd(op + 3, a.w);
    }
}

extern "C" void kernel_launch(void* const* d_in, const int* in_sizes, int n_in,
                              void* d_out, int out_size, void* d_ws, size_t ws_size,
                              hipStream_t stream) {
    const float* feats   = (const float*)d_in[0];
    const float* weight  = (const float*)d_in[1];
    const int*   in_idx  = (const int*)d_in[2];
    const int*   out_idx = (const int*)d_in[3];
    float*       out     = (float*)d_out;

    const size_t feats16_elems = (size_t)N_ROWS * C_IN;          // 16M ushort
    const size_t wT16_elems    = (size_t)K_VOL * C_IN * C_OUT;   // 27,648
    // ints: offsets (NBINS+2 pad) + cursors/counts (NBINS) + bsum (1024) + edge_buf
    const size_t need_bytes = feats16_elems * 2 + wT16_elems * 2 +
        ((size_t)(NBINS + 2) + NBINS + 1024 + E_TOT) * sizeof(int) + 256;

    if (ws_size >= need_bytes) {
        unsigned short* feats16 = (unsigned short*)d_ws;
        unsigned short* wT16    = feats16 + feats16_elems;
        int* offsets = (int*)(wT16 + wT16_elems);     // NBINS+2
        int* cursors = offsets + NBINS + 2;           // NBINS (doubles as counts)
        int* bsum    = cursors + NBINS;               // 1024
        unsigned int* edge_buf = (unsigned int*)(bsum + 1024);  // E_TOT

        hipMemsetAsync(cursors, 0, NBINS * sizeof(int), stream);
        cvt_feats<<<(N_ROWS * C_IN / 8 + 255) / 256, 256, 0, stream>>>(feats, feats16);
        cvt_w<<<(K_VOL * C_IN * C_OUT + 255) / 256, 256, 0, stream>>>(weight, wT16);

        dim3 gEdges4((M_EDGE / 4 + 255) / 256, K_VOL);
        hist_kernel<<<gEdges4, 256, 0, stream>>>(out_idx, cursors);
        scan1_kernel<<<NSCAN_BLK, 1024, 0, stream>>>(cursors, offsets, bsum);
        scan2_kernel<<<1, 1024, 0, stream>>>(bsum);
        scan3_kernel<<<NSCAN_BLK, 1024, 0, stream>>>(offsets, bsum, cursors);
        fill_kernel<<<gEdges4, 256, 0, stream>>>(in_idx, out_idx, cursors, edge_buf);
        conv_mfma2<<<(NT + 3) / 4, 256, 0, stream>>>(feats16, wT16, offsets, edge_buf, out);
    } else {
        hipMemsetAsync(out, 0, (size_t)out_size * sizeof(float), stream);
        dim3 grid((M_EDGE + 1023) / 1024, K_VOL);
        spconv_edges<<<grid, dim3(256), 0, stream>>>(feats, weight, in_idx, out_idx, out);
    }
}

// Round 6
// 671.223 us; speedup vs baseline: 2.6701x; 1.7784x over previous
//
#include <hip/hip_runtime.h>

#define C_IN   32
#define C_OUT  32
#define K_VOL  27
#define M_EDGE 250000
#define N_ROWS 500000
#define E_TOT  (K_VOL * M_EDGE)          // 6,750,000 edges

#define NT        (N_ROWS / 16)          // 31250 row-tiles of 16 rows
#define NREG      977                    // regions of 32 tiles (512 rows): ceil(31250/32)
#define BPB       16                     // fill/hist blocks per k
#define CHUNK     (M_EDGE / BPB)         // 15625 edges per block (exact)
#define NBINS_A   (K_VOL * NREG * BPB)   // 422,064 scan cells: ((k*NREG+r)<<4)+blk
#define NSCAN_BLK ((NBINS_A + 1023) / 1024)  // 413
#define CAPL      40                     // per-(tile,k) LDS list capacity (Poisson(8))

typedef __attribute__((ext_vector_type(8))) short s16x8;   // 8 bf16
typedef __attribute__((ext_vector_type(4))) float f32x4;

static __device__ __forceinline__ unsigned short f2bf(float x) {
    union { float f; unsigned int u; } c; c.f = x;
    const unsigned int r = (c.u + 0x7FFFu + ((c.u >> 16) & 1u)) >> 16;
    return (unsigned short)r;
}
static __device__ __forceinline__ float bf2f(unsigned short s) {
    union { unsigned int u; float f; } c; c.u = ((unsigned int)s) << 16;
    return c.f;
}

// ---------------- Prep: feats fp32 -> bf16 ----------------
__global__ __launch_bounds__(256) void cvt_feats(
    const float* __restrict__ f, unsigned short* __restrict__ o)
{
    const int i = blockIdx.x * 256 + threadIdx.x;
    if (i >= N_ROWS * C_IN / 8) return;
    const float4 v0 = reinterpret_cast<const float4*>(f)[i * 2];
    const float4 v1 = reinterpret_cast<const float4*>(f)[i * 2 + 1];
    s16x8 r;
    r[0] = (short)f2bf(v0.x); r[1] = (short)f2bf(v0.y);
    r[2] = (short)f2bf(v0.z); r[3] = (short)f2bf(v0.w);
    r[4] = (short)f2bf(v1.x); r[5] = (short)f2bf(v1.y);
    r[6] = (short)f2bf(v1.z); r[7] = (short)f2bf(v1.w);
    *reinterpret_cast<s16x8*>(o + (size_t)i * 8) = r;
}

// ---------------- Prep: weight fp32 [k][ci][co] -> bf16 [k][co][ci] ----------------
__global__ __launch_bounds__(256) void cvt_w(
    const float* __restrict__ w, unsigned short* __restrict__ wT)
{
    const int idx = blockIdx.x * 256 + threadIdx.x;
    if (idx >= K_VOL * C_IN * C_OUT) return;
    const int k = idx >> 10, rem = idx & 1023;
    const int co = rem >> 5, ci = rem & 31;
    wT[idx] = f2bf(w[k * 1024 + ci * 32 + co]);
}

// ---------------- Phase A: per-(k,block) region histogram (LDS-aggregated) ----------------
__global__ __launch_bounds__(256) void bhist_kernel(
    const int* __restrict__ out_idx, int* __restrict__ counts)
{
    __shared__ int lh[NREG];
    const int blk = blockIdx.x, k = blockIdx.y, tid = threadIdx.x;
    for (int r = tid; r < NREG; r += 256) lh[r] = 0;
    __syncthreads();
    const int* ob = out_idx + k * M_EDGE + blk * CHUNK;
    for (int t = tid; t < CHUNK; t += 256)
        atomicAdd(&lh[ob[t] >> 9], 1);            // region = row/512
    __syncthreads();
    for (int r = tid; r < NREG; r += 256)
        counts[((k * NREG + r) << 4) + blk] = lh[r];
}

// ---------------- Phase B: two-level exclusive scan over NBINS_A cells ----------------
__global__ __launch_bounds__(1024) void scan1_kernel(
    const int* __restrict__ counts, int* __restrict__ offsets,
    int* __restrict__ bsum)
{
    __shared__ int buf[1024];
    const int tid = threadIdx.x;
    const int i = blockIdx.x * 1024 + tid;
    const int v = (i < NBINS_A) ? counts[i] : 0;
    buf[tid] = v;
    __syncthreads();
    for (int off = 1; off < 1024; off <<= 1) {
        const int t = (tid >= off) ? buf[tid - off] : 0;
        __syncthreads();
        buf[tid] += t;
        __syncthreads();
    }
    if (i < NBINS_A) offsets[i] = buf[tid] - v;
    if (tid == 1023) bsum[blockIdx.x] = buf[1023];
}

__global__ __launch_bounds__(1024) void scan2_kernel(int* __restrict__ bsum)
{
    __shared__ int buf[1024];
    const int tid = threadIdx.x;
    const int v = (tid < NSCAN_BLK) ? bsum[tid] : 0;
    buf[tid] = v;
    __syncthreads();
    for (int off = 1; off < 1024; off <<= 1) {
        const int t = (tid >= off) ? buf[tid - off] : 0;
        __syncthreads();
        buf[tid] += t;
        __syncthreads();
    }
    if (tid < NSCAN_BLK) bsum[tid] = buf[tid] - v;
}

__global__ __launch_bounds__(1024) void scan3_kernel(
    int* __restrict__ offsets, const int* __restrict__ bsum)
{
    const int i = blockIdx.x * 1024 + threadIdx.x;
    if (i < NBINS_A) offsets[i] += bsum[blockIdx.x];
    if (i == 0) offsets[NBINS_A] = E_TOT;   // sentinel = end of last bin
}

// ---------------- Phase C: block-local LDS counting sort, coalesced runs out ----------------
// payload: irow(19) | lrow(4)<<19 | tile-in-region(5)<<23
__global__ __launch_bounds__(256) void fill2_kernel(
    const int* __restrict__ in_idx, const int* __restrict__ out_idx,
    const int* __restrict__ offsA, unsigned int* __restrict__ edge_buf)
{
    __shared__ int base[NREG];
    __shared__ int lh[NREG];
    __shared__ int lstart[NREG + 1];
    __shared__ int lcur[NREG];
    __shared__ int partial[256];
    __shared__ unsigned int pay[CHUNK];          // 61 KB
    const int blk = blockIdx.x, k = blockIdx.y, tid = threadIdx.x;

    for (int r = tid; r < NREG; r += 256) {
        base[r] = offsA[((k * NREG + r) << 4) + blk];
        lh[r] = 0;
    }
    __syncthreads();

    const int eb = k * M_EDGE + blk * CHUNK;
    const int* ob = out_idx + eb;
    const int* ib = in_idx + eb;

    // local histogram
    for (int t = tid; t < CHUNK; t += 256)
        atomicAdd(&lh[ob[t] >> 9], 1);
    __syncthreads();

    // block exclusive scan of lh -> lstart
    int psum = 0;
    const int r0 = tid * 4;
#pragma unroll
    for (int j = 0; j < 4; ++j) { const int r = r0 + j; if (r < NREG) psum += lh[r]; }
    partial[tid] = psum;
    __syncthreads();
    for (int off = 1; off < 256; off <<= 1) {
        const int t = (tid >= off) ? partial[tid - off] : 0;
        __syncthreads();
        partial[tid] += t;
        __syncthreads();
    }
    int run = partial[tid] - psum;
#pragma unroll
    for (int j = 0; j < 4; ++j) {
        const int r = r0 + j;
        if (r < NREG) { lstart[r] = run; lcur[r] = run; run += lh[r]; }
    }
    if (tid == 0) lstart[NREG] = CHUNK;
    __syncthreads();

    // place into region-sorted LDS order
    for (int t = tid; t < CHUNK; t += 256) {
        const int row = ob[t];
        const int irow = ib[t];
        const int idx = atomicAdd(&lcur[row >> 9], 1);
        pay[idx] = (unsigned int)irow | ((unsigned int)(row & 15) << 19) |
                   ((unsigned int)((row >> 4) & 31) << 23);
    }
    __syncthreads();

    // element-parallel copy-out: consecutive q -> consecutive global dst per region
    for (int q = tid; q < CHUNK; q += 256) {
        int lo = 0, hi = NREG;                   // find r: lstart[r] <= q < lstart[r+1]
        while (hi - lo > 1) {
            const int mid = (lo + hi) >> 1;
            if (lstart[mid] <= q) lo = mid; else hi = mid;
        }
        edge_buf[base[lo] + (q - lstart[lo])] = pay[q];
    }
}

// ---------------- Phase D: per-region MFMA conv, LDS bucket, reg accumulate ----------------
// 512 thr = 8 waves; wave owns 4 row-tiles; acc in VGPRs across all 27 k; no atomics.
__global__ __launch_bounds__(512) void conv_mfma3(
    const unsigned short* __restrict__ feats16,
    const unsigned short* __restrict__ wT16,
    const int* __restrict__ offsA,
    const unsigned int* __restrict__ edge_buf,
    float* __restrict__ out)
{
    __shared__ int lcnt[32];
    __shared__ __align__(16) unsigned int lists[32 * CAPL];
    const int g = blockIdx.x;
    const int tid = threadIdx.x;
    const int lane = tid & 63, wv = tid >> 6;
    const int slot = lane & 15, chunk = lane >> 4;

    int myS = 0, myE = 0;
    if (lane < K_VOL) {
        const int bin = lane * NREG + g;
        myS = offsA[bin << 4];                    // block-0 cell = bin start
        myE = offsA[(bin + 1) << 4];              // next bin start (sentinel at end)
    }

    f32x4 a0[4], a1[4];
#pragma unroll
    for (int j = 0; j < 4; ++j) {
        a0[j] = (f32x4){0.f, 0.f, 0.f, 0.f};
        a1[j] = (f32x4){0.f, 0.f, 0.f, 0.f};
    }

#pragma unroll 1
    for (int k = 0; k < K_VOL; ++k) {
        const int s = __builtin_amdgcn_readlane(myS, k);
        const int e = __builtin_amdgcn_readlane(myE, k);
        const int len = e - s;

        if (tid < 32) lcnt[tid] = 0;
        __syncthreads();
        for (int t = tid; t < len; t += 512) {
            const unsigned int p = edge_buf[s + t];
            const int rtl = (int)((p >> 23) & 31u);
            const int idx = atomicAdd(&lcnt[rtl], 1);
            if (idx < CAPL) lists[rtl * CAPL + idx] = p;
        }
        __syncthreads();

        const unsigned short* wk = wT16 + k * (C_IN * C_OUT);
        const s16x8 b0 = *reinterpret_cast<const s16x8*>(wk + slot * 32 + chunk * 8);
        const s16x8 b1 = *reinterpret_cast<const s16x8*>(wk + (slot + 16) * 32 + chunk * 8);

#pragma unroll
        for (int j = 0; j < 4; ++j) {
            const int rtl = wv * 4 + j;
            const int rtg = g * 32 + rtl;
            int n = lcnt[rtl]; if (n > CAPL) n = CAPL;
            if (rtg < NT && n > 0) {
                float af[8] = {0.f, 0.f, 0.f, 0.f, 0.f, 0.f, 0.f, 0.f};
#pragma unroll 1
                for (int jj = 0; jj < n; jj += 4) {
                    const uint4 pw = *reinterpret_cast<const uint4*>(&lists[rtl * CAPL + jj]);
                    s16x8 f0 = {0,0,0,0,0,0,0,0}, f1 = {0,0,0,0,0,0,0,0};
                    s16x8 f2 = {0,0,0,0,0,0,0,0}, f3 = {0,0,0,0,0,0,0,0};
                    if (((pw.x >> 19) & 15u) == (unsigned)slot)
                        f0 = *reinterpret_cast<const s16x8*>(
                            feats16 + (size_t)(pw.x & 0x7FFFFu) * C_IN + chunk * 8);
                    if (jj + 1 < n && ((pw.y >> 19) & 15u) == (unsigned)slot)
                        f1 = *reinterpret_cast<const s16x8*>(
                            feats16 + (size_t)(pw.y & 0x7FFFFu) * C_IN + chunk * 8);
                    if (jj + 2 < n && ((pw.z >> 19) & 15u) == (unsigned)slot)
                        f2 = *reinterpret_cast<const s16x8*>(
                            feats16 + (size_t)(pw.z & 0x7FFFFu) * C_IN + chunk * 8);
                    if (jj + 3 < n && ((pw.w >> 19) & 15u) == (unsigned)slot)
                        f3 = *reinterpret_cast<const s16x8*>(
                            feats16 + (size_t)(pw.w & 0x7FFFFu) * C_IN + chunk * 8);
#pragma unroll
                    for (int q = 0; q < 8; ++q)
                        af[q] += (bf2f((unsigned short)f0[q]) + bf2f((unsigned short)f1[q])) +
                                 (bf2f((unsigned short)f2[q]) + bf2f((unsigned short)f3[q]));
                }
                s16x8 a;
#pragma unroll
                for (int q = 0; q < 8; ++q) a[q] = (short)f2bf(af[q]);
                a0[j] = __builtin_amdgcn_mfma_f32_16x16x32_bf16(a, b0, a0[j], 0, 0, 0);
                a1[j] = __builtin_amdgcn_mfma_f32_16x16x32_bf16(a, b1, a1[j], 0, 0, 0);
            }
        }
        __syncthreads();
    }

    // D layout: col = lane&15, row = chunk*4 + jj
#pragma unroll
    for (int j = 0; j < 4; ++j) {
        const int rtg = g * 32 + wv * 4 + j;
        if (rtg < NT) {
            const int r0 = rtg * 16 + chunk * 4;
#pragma unroll
            for (int jj = 0; jj < 4; ++jj) {
                out[(size_t)(r0 + jj) * C_OUT + slot]      = a0[j][jj];
                out[(size_t)(r0 + jj) * C_OUT + 16 + slot] = a1[j][jj];
            }
        }
    }
}

// ---------------- Fallback (edge-atomic) if ws too small ----------------
__global__ __launch_bounds__(256) void spconv_edges(
    const float* __restrict__ feats, const float* __restrict__ weight,
    const int* __restrict__ in_idx, const int* __restrict__ out_idx,
    float* __restrict__ out)
{
    const int k = blockIdx.y;
    const int tid = threadIdx.x;
    const int g = tid >> 3, l = tid & 7, c0 = l * 4;
    const float* wk = weight + k * (C_IN * C_OUT);
    float4 wr[32];
#pragma unroll
    for (int ci = 0; ci < 32; ++ci)
        wr[ci] = *reinterpret_cast<const float4*>(wk + ci * C_OUT + c0);
    const int* ik = in_idx + k * M_EDGE;
    const int* ok = out_idx + k * M_EDGE;
    int m = blockIdx.x * 1024 + g;
#pragma unroll 1
    for (int it = 0; it < 32; ++it, m += 32) {
        if (m >= M_EDGE) break;
        const int irow = ik[m], orow = ok[m];
        const float4* frow =
            reinterpret_cast<const float4*>(feats + (size_t)irow * C_IN);
        float4 a = make_float4(0.f, 0.f, 0.f, 0.f);
#pragma unroll
        for (int j = 0; j < 8; ++j) {
            const float4 f4 = frow[j];
            const float fv[4] = {f4.x, f4.y, f4.z, f4.w};
#pragma unroll
            for (int t = 0; t < 4; ++t) {
                const float4 w4 = wr[j * 4 + t];
                a.x = fmaf(fv[t], w4.x, a.x);
                a.y = fmaf(fv[t], w4.y, a.y);
                a.z = fmaf(fv[t], w4.z, a.z);
                a.w = fmaf(fv[t], w4.w, a.w);
            }
        }
        float* op = out + (size_t)orow * C_OUT + c0;
        unsafeAtomicAdd(op + 0, a.x);
        unsafeAtomicAdd(op + 1, a.y);
        unsafeAtomicAdd(op + 2, a.z);
        unsafeAtomicAdd(op + 3, a.w);
    }
}

extern "C" void kernel_launch(void* const* d_in, const int* in_sizes, int n_in,
                              void* d_out, int out_size, void* d_ws, size_t ws_size,
                              hipStream_t stream) {
    const float* feats   = (const float*)d_in[0];
    const float* weight  = (const float*)d_in[1];
    const int*   in_idx  = (const int*)d_in[2];
    const int*   out_idx = (const int*)d_in[3];
    float*       out     = (float*)d_out;

    const size_t feats16_elems = (size_t)N_ROWS * C_IN;          // 16M ushort
    const size_t wT16_elems    = (size_t)K_VOL * C_IN * C_OUT;   // 27,648
    const size_t need_bytes = feats16_elems * 2 + wT16_elems * 2 +
        ((size_t)NBINS_A + (NBINS_A + 1) + 1024 + E_TOT) * sizeof(int) + 256;  // ~62.4 MB

    if (ws_size >= need_bytes) {
        unsigned short* feats16 = (unsigned short*)d_ws;
        unsigned short* wT16    = feats16 + feats16_elems;
        int* counts = (int*)(wT16 + wT16_elems);              // NBINS_A
        int* offsA  = counts + NBINS_A;                       // NBINS_A + 1
        int* bsum   = offsA + NBINS_A + 1;                    // 1024
        unsigned int* edge_buf = (unsigned int*)(bsum + 1024);// E_TOT

        cvt_feats<<<(N_ROWS * C_IN / 8 + 255) / 256, 256, 0, stream>>>(feats, feats16);
        cvt_w<<<(K_VOL * C_IN * C_OUT + 255) / 256, 256, 0, stream>>>(weight, wT16);

        dim3 gKB(BPB, K_VOL);
        bhist_kernel<<<gKB, 256, 0, stream>>>(out_idx, counts);
        scan1_kernel<<<NSCAN_BLK, 1024, 0, stream>>>(counts, offsA, bsum);
        scan2_kernel<<<1, 1024, 0, stream>>>(bsum);
        scan3_kernel<<<NSCAN_BLK, 1024, 0, stream>>>(offsA, bsum);
        fill2_kernel<<<gKB, 256, 0, stream>>>(in_idx, out_idx, offsA, edge_buf);
        conv_mfma3<<<NREG, 512, 0, stream>>>(feats16, wT16, offsA, edge_buf, out);
    } else {
        hipMemsetAsync(out, 0, (size_t)out_size * sizeof(float), stream);
        dim3 grid((M_EDGE + 1023) / 1024, K_VOL);
        spconv_edges<<<grid, dim3(256), 0, stream>>>(feats, weight, in_idx, out_idx, out);
    }
}

// Round 8
// 444.722 us; speedup vs baseline: 4.0300x; 1.5093x over previous
//
#include <hip/hip_runtime.h>

#define C_IN   32
#define C_OUT  32
#define K_VOL  27
#define M_EDGE 250000
#define N_ROWS 500000
#define E_TOT  (K_VOL * M_EDGE)          // 6,750,000 edges

#define NT        (N_ROWS / 16)          // 31250 row-tiles of 16 rows
#define NREG      977                    // regions of 32 tiles (512 rows)
#define BPB       16                     // fill/hist blocks per k
#define CHUNK     (M_EDGE / BPB)         // 15625 edges per block
#define NBINS_A   (K_VOL * NREG * BPB)   // 422,064 scan cells
#define NSCAN_BLK ((NBINS_A + 1023) / 1024)  // 413
#define NLISTS    512                    // per-(tile,row) lists in conv
#define CAPL      16                     // list capacity: P(Pois(0.5)>16) ~ 1e-19
#define LSTRIDE   17                     // pad stride to spread LDS banks

typedef __attribute__((ext_vector_type(8))) short s16x8;   // 8 bf16
typedef __attribute__((ext_vector_type(4))) float f32x4;

static __device__ __forceinline__ unsigned short f2bf(float x) {
    union { float f; unsigned int u; } c; c.f = x;
    const unsigned int r = (c.u + 0x7FFFu + ((c.u >> 16) & 1u)) >> 16;
    return (unsigned short)r;
}
static __device__ __forceinline__ float bf2f(unsigned short s) {
    union { unsigned int u; float f; } c; c.u = ((unsigned int)s) << 16;
    return c.f;
}
// pack 2 f32 -> 2 bf16 (RNE); dst.lo = bf16(lo), dst.hi = bf16(hi)  [T12, HW-verified]
static __device__ __forceinline__ unsigned int cvtpk(float lo, float hi) {
    unsigned int r;
    asm("v_cvt_pk_bf16_f32 %0, %1, %2" : "=v"(r) : "v"(lo), "v"(hi));
    return r;
}

// ---------------- Prep: feats fp32 -> bf16 ----------------
__global__ __launch_bounds__(256) void cvt_feats(
    const float* __restrict__ f, unsigned short* __restrict__ o)
{
    const int i = blockIdx.x * 256 + threadIdx.x;
    if (i >= N_ROWS * C_IN / 8) return;
    const float4 v0 = reinterpret_cast<const float4*>(f)[i * 2];
    const float4 v1 = reinterpret_cast<const float4*>(f)[i * 2 + 1];
    s16x8 r;
    r[0] = (short)f2bf(v0.x); r[1] = (short)f2bf(v0.y);
    r[2] = (short)f2bf(v0.z); r[3] = (short)f2bf(v0.w);
    r[4] = (short)f2bf(v1.x); r[5] = (short)f2bf(v1.y);
    r[6] = (short)f2bf(v1.z); r[7] = (short)f2bf(v1.w);
    *reinterpret_cast<s16x8*>(o + (size_t)i * 8) = r;
}

// ---------------- Prep: weight fp32 [k][ci][co] -> bf16 [k][co][ci] ----------------
__global__ __launch_bounds__(256) void cvt_w(
    const float* __restrict__ w, unsigned short* __restrict__ wT)
{
    const int idx = blockIdx.x * 256 + threadIdx.x;
    if (idx >= K_VOL * C_IN * C_OUT) return;
    const int k = idx >> 10, rem = idx & 1023;
    const int co = rem >> 5, ci = rem & 31;
    wT[idx] = f2bf(w[k * 1024 + ci * 32 + co]);
}

// ---------------- Phase A: per-(k,block) region histogram (LDS-aggregated) ----------------
__global__ __launch_bounds__(256) void bhist_kernel(
    const int* __restrict__ out_idx, int* __restrict__ counts)
{
    __shared__ int lh[NREG];
    const int blk = blockIdx.x, k = blockIdx.y, tid = threadIdx.x;
    for (int r = tid; r < NREG; r += 256) lh[r] = 0;
    __syncthreads();
    const int* ob = out_idx + k * M_EDGE + blk * CHUNK;
    for (int t = tid; t < CHUNK; t += 256)
        atomicAdd(&lh[ob[t] >> 9], 1);            // region = row/512
    __syncthreads();
    for (int r = tid; r < NREG; r += 256)
        counts[((k * NREG + r) << 4) + blk] = lh[r];
}

// ---------------- Phase B: two-level exclusive scan over NBINS_A cells ----------------
__global__ __launch_bounds__(1024) void scan1_kernel(
    const int* __restrict__ counts, int* __restrict__ offsets,
    int* __restrict__ bsum)
{
    __shared__ int buf[1024];
    const int tid = threadIdx.x;
    const int i = blockIdx.x * 1024 + tid;
    const int v = (i < NBINS_A) ? counts[i] : 0;
    buf[tid] = v;
    __syncthreads();
    for (int off = 1; off < 1024; off <<= 1) {
        const int t = (tid >= off) ? buf[tid - off] : 0;
        __syncthreads();
        buf[tid] += t;
        __syncthreads();
    }
    if (i < NBINS_A) offsets[i] = buf[tid] - v;
    if (tid == 1023) bsum[blockIdx.x] = buf[1023];
}

__global__ __launch_bounds__(1024) void scan2_kernel(int* __restrict__ bsum)
{
    __shared__ int buf[1024];
    const int tid = threadIdx.x;
    const int v = (tid < NSCAN_BLK) ? bsum[tid] : 0;
    buf[tid] = v;
    __syncthreads();
    for (int off = 1; off < 1024; off <<= 1) {
        const int t = (tid >= off) ? buf[tid - off] : 0;
        __syncthreads();
        buf[tid] += t;
        __syncthreads();
    }
    if (tid < NSCAN_BLK) bsum[tid] = buf[tid] - v;
}

__global__ __launch_bounds__(1024) void scan3_kernel(
    int* __restrict__ offsets, const int* __restrict__ bsum)
{
    const int i = blockIdx.x * 1024 + threadIdx.x;
    if (i < NBINS_A) offsets[i] += bsum[blockIdx.x];
    if (i == 0) offsets[NBINS_A] = E_TOT;   // sentinel
}

// ---------------- Phase C: block-local LDS counting sort, coalesced runs out ----------------
// payload: irow(19) | lrow(4)<<19 | tile-in-region(5)<<23
__global__ __launch_bounds__(256) void fill2_kernel(
    const int* __restrict__ in_idx, const int* __restrict__ out_idx,
    const int* __restrict__ offsA, unsigned int* __restrict__ edge_buf)
{
    __shared__ int base[NREG];
    __shared__ int lh[NREG];
    __shared__ int lstart[NREG + 1];
    __shared__ int lcur[NREG];
    __shared__ int partial[256];
    __shared__ unsigned int pay[CHUNK];          // 61 KB
    const int blk = blockIdx.x, k = blockIdx.y, tid = threadIdx.x;

    for (int r = tid; r < NREG; r += 256) {
        base[r] = offsA[((k * NREG + r) << 4) + blk];
        lh[r] = 0;
    }
    __syncthreads();

    const int eb = k * M_EDGE + blk * CHUNK;
    const int* ob = out_idx + eb;
    const int* ib = in_idx + eb;

    for (int t = tid; t < CHUNK; t += 256)
        atomicAdd(&lh[ob[t] >> 9], 1);
    __syncthreads();

    int psum = 0;
    const int r0 = tid * 4;
#pragma unroll
    for (int j = 0; j < 4; ++j) { const int r = r0 + j; if (r < NREG) psum += lh[r]; }
    partial[tid] = psum;
    __syncthreads();
    for (int off = 1; off < 256; off <<= 1) {
        const int t = (tid >= off) ? partial[tid - off] : 0;
        __syncthreads();
        partial[tid] += t;
        __syncthreads();
    }
    int run = partial[tid] - psum;
#pragma unroll
    for (int j = 0; j < 4; ++j) {
        const int r = r0 + j;
        if (r < NREG) { lstart[r] = run; lcur[r] = run; run += lh[r]; }
    }
    if (tid == 0) lstart[NREG] = CHUNK;
    __syncthreads();

    for (int t = tid; t < CHUNK; t += 256) {
        const int row = ob[t];
        const int irow = ib[t];
        const int idx = atomicAdd(&lcur[row >> 9], 1);
        pay[idx] = (unsigned int)irow | ((unsigned int)(row & 15) << 19) |
                   ((unsigned int)((row >> 4) & 31) << 23);
    }
    __syncthreads();

    for (int q = tid; q < CHUNK; q += 256) {
        int lo = 0, hi = NREG;
        while (hi - lo > 1) {
            const int mid = (lo + hi) >> 1;
            if (lstart[mid] <= q) lo = mid; else hi = mid;
        }
        edge_buf[base[lo] + (q - lstart[lo])] = pay[q];
    }
}

// ---------------- Phase D: per-(tile,row) list MFMA conv ----------------
// 512 thr = 8 waves; wave owns 4 row-tiles; 512 LDS lists keyed by
// (tile-in-region, row-in-tile). Lane (slot,chunk) walks ONLY its row's list:
// no masks, no wasted unpacks. MFMA accumulates across all 27 k in VGPRs.
__global__ __launch_bounds__(512) void conv_mfma5(
    const unsigned short* __restrict__ feats16,
    const unsigned short* __restrict__ wT16,
    const int* __restrict__ offsA,
    const unsigned int* __restrict__ edge_buf,
    float* __restrict__ out)
{
    __shared__ int lcnt[NLISTS];
    __shared__ unsigned int lists[NLISTS * LSTRIDE];   // 34.8 KB
    const int g = blockIdx.x;
    const int tid = threadIdx.x;
    const int lane = tid & 63, wv = tid >> 6;
    const int slot = lane & 15, chunk = lane >> 4;

    int myS = 0, myE = 0;
    if (lane < K_VOL) {
        const int bin = lane * NREG + g;
        myS = offsA[bin << 4];
        myE = offsA[(bin + 1) << 4];
    }

    f32x4 a0[4], a1[4];
#pragma unroll
    for (int j = 0; j < 4; ++j) {
        a0[j] = (f32x4){0.f, 0.f, 0.f, 0.f};
        a1[j] = (f32x4){0.f, 0.f, 0.f, 0.f};
    }

#pragma unroll 1
    for (int k = 0; k < K_VOL; ++k) {
        const int s = __builtin_amdgcn_readlane(myS, k);
        const int e = __builtin_amdgcn_readlane(myE, k);
        const int len = e - s;

        lcnt[tid] = 0;                      // 512 threads cover 512 counters
        __syncthreads();
        // bucket this region's k-segment by (tile,row); store bare irow
        for (int t = tid; t < len; t += 512) {
            const unsigned int p = edge_buf[s + t];
            const int li = (int)((p >> 19) & 0x1FFu);   // tile*16 + lrow
            const int idx = atomicAdd(&lcnt[li], 1);
            if (idx < CAPL) lists[li * LSTRIDE + idx] = p & 0x7FFFFu;
        }
        __syncthreads();

        // W_k B-fragments: lane holds W[co=slot(+16)][ci=chunk*8..+7]
        const unsigned short* wk = wT16 + k * (C_IN * C_OUT);
        const s16x8 b0 = *reinterpret_cast<const s16x8*>(wk + slot * 32 + chunk * 8);
        const s16x8 b1 = *reinterpret_cast<const s16x8*>(wk + (slot + 16) * 32 + chunk * 8);

#pragma unroll
        for (int j = 0; j < 4; ++j) {
            const int rtl = wv * 4 + j;
            if (g * 32 + rtl >= NT) continue;          // wave-uniform
            const int li = rtl * 16 + slot;
            int myc = lcnt[li]; if (myc > CAPL) myc = CAPL;
            const unsigned int* lp = &lists[li * LSTRIDE];

            float af[8] = {0.f, 0.f, 0.f, 0.f, 0.f, 0.f, 0.f, 0.f};
#pragma unroll 1
            for (int i = 0; ; ++i) {
                if (!__any(i < myc)) break;            // wave-max loop bound
                s16x8 f = {0, 0, 0, 0, 0, 0, 0, 0};
                if (i < myc) {
                    const unsigned int irow = lp[i];
                    f = *reinterpret_cast<const s16x8*>(
                        feats16 + (size_t)irow * C_IN + chunk * 8);
                }
#pragma unroll
                for (int q = 0; q < 8; ++q) af[q] += bf2f((unsigned short)f[q]);
            }

            union { unsigned int w[4]; s16x8 v; } A;
            A.w[0] = cvtpk(af[0], af[1]);
            A.w[1] = cvtpk(af[2], af[3]);
            A.w[2] = cvtpk(af[4], af[5]);
            A.w[3] = cvtpk(af[6], af[7]);
            a0[j] = __builtin_amdgcn_mfma_f32_16x16x32_bf16(A.v, b0, a0[j], 0, 0, 0);
            a1[j] = __builtin_amdgcn_mfma_f32_16x16x32_bf16(A.v, b1, a1[j], 0, 0, 0);
        }
        __syncthreads();
    }

    // D layout: col = lane&15, row = chunk*4 + jj
#pragma unroll
    for (int j = 0; j < 4; ++j) {
        const int rtg = g * 32 + wv * 4 + j;
        if (rtg < NT) {
            const int r0 = rtg * 16 + chunk * 4;
#pragma unroll
            for (int jj = 0; jj < 4; ++jj) {
                out[(size_t)(r0 + jj) * C_OUT + slot]      = a0[j][jj];
                out[(size_t)(r0 + jj) * C_OUT + 16 + slot] = a1[j][jj];
            }
        }
    }
}

// ---------------- Fallback (edge-atomic) if ws too small ----------------
__global__ __launch_bounds__(256) void spconv_edges(
    const float* __restrict__ feats, const float* __restrict__ weight,
    const int* __restrict__ in_idx, const int* __restrict__ out_idx,
    float* __restrict__ out)
{
    const int k = blockIdx.y;
    const int tid = threadIdx.x;
    const int g = tid >> 3, l = tid & 7, c0 = l * 4;
    const float* wk = weight + k * (C_IN * C_OUT);
    float4 wr[32];
#pragma unroll
    for (int ci = 0; ci < 32; ++ci)
        wr[ci] = *reinterpret_cast<const float4*>(wk + ci * C_OUT + c0);
    const int* ik = in_idx + k * M_EDGE;
    const int* ok = out_idx + k * M_EDGE;
    int m = blockIdx.x * 1024 + g;
#pragma unroll 1
    for (int it = 0; it < 32; ++it, m += 32) {
        if (m >= M_EDGE) break;
        const int irow = ik[m], orow = ok[m];
        const float4* frow =
            reinterpret_cast<const float4*>(feats + (size_t)irow * C_IN);
        float4 a = make_float4(0.f, 0.f, 0.f, 0.f);
#pragma unroll
        for (int j = 0; j < 8; ++j) {
            const float4 f4 = frow[j];
            const float fv[4] = {f4.x, f4.y, f4.z, f4.w};
#pragma unroll
            for (int t = 0; t < 4; ++t) {
                const float4 w4 = wr[j * 4 + t];
                a.x = fmaf(fv[t], w4.x, a.x);
                a.y = fmaf(fv[t], w4.y, a.y);
                a.z = fmaf(fv[t], w4.z, a.z);
                a.w = fmaf(fv[t], w4.w, a.w);
            }
        }
        float* op = out + (size_t)orow * C_OUT + c0;
        unsafeAtomicAdd(op + 0, a.x);
        unsafeAtomicAdd(op + 1, a.y);
        unsafeAtomicAdd(op + 2, a.z);
        unsafeAtomicAdd(op + 3, a.w);
    }
}

extern "C" void kernel_launch(void* const* d_in, const int* in_sizes, int n_in,
                              void* d_out, int out_size, void* d_ws, size_t ws_size,
                              hipStream_t stream) {
    const float* feats   = (const float*)d_in[0];
    const float* weight  = (const float*)d_in[1];
    const int*   in_idx  = (const int*)d_in[2];
    const int*   out_idx = (const int*)d_in[3];
    float*       out     = (float*)d_out;

    const size_t feats16_elems = (size_t)N_ROWS * C_IN;          // 16M ushort
    const size_t wT16_elems    = (size_t)K_VOL * C_IN * C_OUT;   // 27,648
    const size_t need_bytes = feats16_elems * 2 + wT16_elems * 2 +
        ((size_t)NBINS_A + (NBINS_A + 1) + 1024 + E_TOT) * sizeof(int) + 256;

    if (ws_size >= need_bytes) {
        unsigned short* feats16 = (unsigned short*)d_ws;
        unsigned short* wT16    = feats16 + feats16_elems;
        int* counts = (int*)(wT16 + wT16_elems);              // NBINS_A
        int* offsA  = counts + NBINS_A;                       // NBINS_A + 1
        int* bsum   = offsA + NBINS_A + 1;                    // 1024
        unsigned int* edge_buf = (unsigned int*)(bsum + 1024);// E_TOT

        cvt_feats<<<(N_ROWS * C_IN / 8 + 255) / 256, 256, 0, stream>>>(feats, feats16);
        cvt_w<<<(K_VOL * C_IN * C_OUT + 255) / 256, 256, 0, stream>>>(weight, wT16);

        dim3 gKB(BPB, K_VOL);
        bhist_kernel<<<gKB, 256, 0, stream>>>(out_idx, counts);
        scan1_kernel<<<NSCAN_BLK, 1024, 0, stream>>>(counts, offsA, bsum);
        scan2_kernel<<<1, 1024, 0, stream>>>(bsum);
        scan3_kernel<<<NSCAN_BLK, 1024, 0, stream>>>(offsA, bsum);
        fill2_kernel<<<gKB, 256, 0, stream>>>(in_idx, out_idx, offsA, edge_buf);
        conv_mfma5<<<NREG, 512, 0, stream>>>(feats16, wT16, offsA, edge_buf, out);
    } else {
        hipMemsetAsync(out, 0, (size_t)out_size * sizeof(float), stream);
        dim3 grid((M_EDGE + 1023) / 1024, K_VOL);
        spconv_edges<<<grid, dim3(256), 0, stream>>>(feats, weight, in_idx, out_idx, out);
    }
}

// Round 9
// 345.908 us; speedup vs baseline: 5.1813x; 1.2857x over previous
//
#include <hip/hip_runtime.h>

#define C_IN   32
#define C_OUT  32
#define K_VOL  27
#define M_EDGE 250000
#define N_ROWS 500000
#define E_TOT  (K_VOL * M_EDGE)          // 6,750,000 edges

#define NT        (N_ROWS / 16)          // 31250 row-tiles of 16 rows
#define NREG      977                    // regions of 32 tiles (512 rows)
#define BPB       16                     // fill/hist blocks per k
#define CHUNK     (M_EDGE / BPB)         // 15625 edges per block
#define NBINS_A   (K_VOL * NREG * BPB)   // 422,064 scan cells
#define NSCAN_BLK ((NBINS_A + 1023) / 1024)  // 413
#define NLISTS    512                    // per-(tile,row) lists in conv
#define CAPL      16                     // list capacity: P(Pois(0.5)>16) ~ 1e-19
#define LSTRIDE   17                     // pad stride: 17*s mod 32 distinct for s=0..15

typedef __attribute__((ext_vector_type(8))) short s16x8;   // 8 bf16
typedef __attribute__((ext_vector_type(4))) float f32x4;

static __device__ __forceinline__ unsigned short f2bf(float x) {
    union { float f; unsigned int u; } c; c.f = x;
    const unsigned int r = (c.u + 0x7FFFu + ((c.u >> 16) & 1u)) >> 16;
    return (unsigned short)r;
}
// pack 2 f32 -> 2 bf16 (RNE); dst.lo = bf16(lo), dst.hi = bf16(hi)
static __device__ __forceinline__ unsigned int cvtpk(float lo, float hi) {
    unsigned int r;
    asm("v_cvt_pk_bf16_f32 %0, %1, %2" : "=v"(r) : "v"(lo), "v"(hi));
    return r;
}
// af[d] accumulates (channel 2d, channel 2d+1) as f32 pair (packed-add friendly)
static __device__ __forceinline__ void unpack_add(float2* af, const s16x8& f) {
    union { s16x8 v; unsigned int w[4]; } u; u.v = f;
#pragma unroll
    for (int d = 0; d < 4; ++d) {
        af[d].x += __uint_as_float(u.w[d] << 16);          // even channel (low short)
        af[d].y += __uint_as_float(u.w[d] & 0xffff0000u);  // odd channel (high short)
    }
}

// ---------------- Prep: feats fp32 -> bf16 ----------------
__global__ __launch_bounds__(256) void cvt_feats(
    const float* __restrict__ f, unsigned short* __restrict__ o)
{
    const int i = blockIdx.x * 256 + threadIdx.x;
    if (i >= N_ROWS * C_IN / 8) return;
    const float4 v0 = reinterpret_cast<const float4*>(f)[i * 2];
    const float4 v1 = reinterpret_cast<const float4*>(f)[i * 2 + 1];
    s16x8 r;
    r[0] = (short)f2bf(v0.x); r[1] = (short)f2bf(v0.y);
    r[2] = (short)f2bf(v0.z); r[3] = (short)f2bf(v0.w);
    r[4] = (short)f2bf(v1.x); r[5] = (short)f2bf(v1.y);
    r[6] = (short)f2bf(v1.z); r[7] = (short)f2bf(v1.w);
    *reinterpret_cast<s16x8*>(o + (size_t)i * 8) = r;
}

// ---------------- Prep: weight fp32 [k][ci][co] -> bf16 [k][co][ci] ----------------
__global__ __launch_bounds__(256) void cvt_w(
    const float* __restrict__ w, unsigned short* __restrict__ wT)
{
    const int idx = blockIdx.x * 256 + threadIdx.x;
    if (idx >= K_VOL * C_IN * C_OUT) return;
    const int k = idx >> 10, rem = idx & 1023;
    const int co = rem >> 5, ci = rem & 31;
    wT[idx] = f2bf(w[k * 1024 + ci * 32 + co]);
}

// ---------------- Phase A: per-(k,block) region histogram (LDS-aggregated) ----------------
__global__ __launch_bounds__(256) void bhist_kernel(
    const int* __restrict__ out_idx, int* __restrict__ counts)
{
    __shared__ int lh[NREG];
    const int blk = blockIdx.x, k = blockIdx.y, tid = threadIdx.x;
    for (int r = tid; r < NREG; r += 256) lh[r] = 0;
    __syncthreads();
    const int* ob = out_idx + k * M_EDGE + blk * CHUNK;
    for (int t = tid; t < CHUNK; t += 256)
        atomicAdd(&lh[ob[t] >> 9], 1);            // region = row/512
    __syncthreads();
    for (int r = tid; r < NREG; r += 256)
        counts[((k * NREG + r) << 4) + blk] = lh[r];
}

// ---------------- Phase B: two-level exclusive scan over NBINS_A cells ----------------
__global__ __launch_bounds__(1024) void scan1_kernel(
    const int* __restrict__ counts, int* __restrict__ offsets,
    int* __restrict__ bsum)
{
    __shared__ int buf[1024];
    const int tid = threadIdx.x;
    const int i = blockIdx.x * 1024 + tid;
    const int v = (i < NBINS_A) ? counts[i] : 0;
    buf[tid] = v;
    __syncthreads();
    for (int off = 1; off < 1024; off <<= 1) {
        const int t = (tid >= off) ? buf[tid - off] : 0;
        __syncthreads();
        buf[tid] += t;
        __syncthreads();
    }
    if (i < NBINS_A) offsets[i] = buf[tid] - v;
    if (tid == 1023) bsum[blockIdx.x] = buf[1023];
}

__global__ __launch_bounds__(1024) void scan2_kernel(int* __restrict__ bsum)
{
    __shared__ int buf[1024];
    const int tid = threadIdx.x;
    const int v = (tid < NSCAN_BLK) ? bsum[tid] : 0;
    buf[tid] = v;
    __syncthreads();
    for (int off = 1; off < 1024; off <<= 1) {
        const int t = (tid >= off) ? buf[tid - off] : 0;
        __syncthreads();
        buf[tid] += t;
        __syncthreads();
    }
    if (tid < NSCAN_BLK) bsum[tid] = buf[tid] - v;
}

__global__ __launch_bounds__(1024) void scan3_kernel(
    int* __restrict__ offsets, const int* __restrict__ bsum)
{
    const int i = blockIdx.x * 1024 + threadIdx.x;
    if (i < NBINS_A) offsets[i] += bsum[blockIdx.x];
    if (i == 0) offsets[NBINS_A] = E_TOT;   // sentinel
}

// ---------------- Phase C: block-local LDS counting sort, coalesced runs out ----------------
// payload: irow(19) | lrow(4)<<19 | tile-in-region(5)<<23
__global__ __launch_bounds__(256) void fill2_kernel(
    const int* __restrict__ in_idx, const int* __restrict__ out_idx,
    const int* __restrict__ offsA, unsigned int* __restrict__ edge_buf)
{
    __shared__ int base[NREG];
    __shared__ int lh[NREG];
    __shared__ int lstart[NREG + 1];
    __shared__ int lcur[NREG];
    __shared__ int partial[256];
    __shared__ unsigned int pay[CHUNK];          // 61 KB
    const int blk = blockIdx.x, k = blockIdx.y, tid = threadIdx.x;

    for (int r = tid; r < NREG; r += 256) {
        base[r] = offsA[((k * NREG + r) << 4) + blk];
        lh[r] = 0;
    }
    __syncthreads();

    const int eb = k * M_EDGE + blk * CHUNK;
    const int* ob = out_idx + eb;
    const int* ib = in_idx + eb;

    for (int t = tid; t < CHUNK; t += 256)
        atomicAdd(&lh[ob[t] >> 9], 1);
    __syncthreads();

    int psum = 0;
    const int r0 = tid * 4;
#pragma unroll
    for (int j = 0; j < 4; ++j) { const int r = r0 + j; if (r < NREG) psum += lh[r]; }
    partial[tid] = psum;
    __syncthreads();
    for (int off = 1; off < 256; off <<= 1) {
        const int t = (tid >= off) ? partial[tid - off] : 0;
        __syncthreads();
        partial[tid] += t;
        __syncthreads();
    }
    int run = partial[tid] - psum;
#pragma unroll
    for (int j = 0; j < 4; ++j) {
        const int r = r0 + j;
        if (r < NREG) { lstart[r] = run; lcur[r] = run; run += lh[r]; }
    }
    if (tid == 0) lstart[NREG] = CHUNK;
    __syncthreads();

    for (int t = tid; t < CHUNK; t += 256) {
        const int row = ob[t];
        const int irow = ib[t];
        const int idx = atomicAdd(&lcur[row >> 9], 1);
        pay[idx] = (unsigned int)irow | ((unsigned int)(row & 15) << 19) |
                   ((unsigned int)((row >> 4) & 31) << 23);
    }
    __syncthreads();

    for (int q = tid; q < CHUNK; q += 256) {
        int lo = 0, hi = NREG;
        while (hi - lo > 1) {
            const int mid = (lo + hi) >> 1;
            if (lstart[mid] <= q) lo = mid; else hi = mid;
        }
        edge_buf[base[lo] + (q - lstart[lo])] = pay[q];
    }
}

// ---------------- Phase D: per-(tile,row) list MFMA conv, depth-2 gather prefetch ----------------
// 512 thr = 8 waves; wave owns 4 row-tiles. Per k: bucket segment into 512
// (tile,row) lists, then read counts + first 2 entries for ALL 4 tiles and
// issue up to 8 independent gathers before any unpack (MLP ~8 vs ~1).
// Residual (count>=3, ~21%/tile) handled by a rare serial tail loop.
__global__ __launch_bounds__(512, 4) void conv_mfma6(
    const unsigned short* __restrict__ feats16,
    const unsigned short* __restrict__ wT16,
    const int* __restrict__ offsA,
    const unsigned int* __restrict__ edge_buf,
    float* __restrict__ out)
{
    __shared__ int lcnt[NLISTS];
    __shared__ unsigned int lists[NLISTS * LSTRIDE];   // 34.8 KB
    const int g = blockIdx.x;
    const int tid = threadIdx.x;
    const int lane = tid & 63, wv = tid >> 6;
    const int slot = lane & 15, chunk = lane >> 4;

    int myS = 0, myE = 0;
    if (lane < K_VOL) {
        const int bin = lane * NREG + g;
        myS = offsA[bin << 4];
        myE = offsA[(bin + 1) << 4];
    }

    f32x4 a0[4], a1[4];
#pragma unroll
    for (int j = 0; j < 4; ++j) {
        a0[j] = (f32x4){0.f, 0.f, 0.f, 0.f};
        a1[j] = (f32x4){0.f, 0.f, 0.f, 0.f};
    }

#pragma unroll 1
    for (int k = 0; k < K_VOL; ++k) {
        const int s = __builtin_amdgcn_readlane(myS, k);
        const int e = __builtin_amdgcn_readlane(myE, k);
        const int len = e - s;

        lcnt[tid] = 0;                      // 512 threads cover 512 counters
        __syncthreads();
        for (int t = tid; t < len; t += 512) {
            const unsigned int p = edge_buf[s + t];
            const int li = (int)((p >> 19) & 0x1FFu);   // tile*16 + lrow
            const int idx = atomicAdd(&lcnt[li], 1);
            if (idx < CAPL) lists[li * LSTRIDE + idx] = p & 0x7FFFFu;
        }
        __syncthreads();

        // W_k B-fragments: lane holds W[co=slot(+16)][ci=chunk*8..+7]
        const unsigned short* wk = wT16 + k * (C_IN * C_OUT);
        const s16x8 b0 = *reinterpret_cast<const s16x8*>(wk + slot * 32 + chunk * 8);
        const s16x8 b1 = *reinterpret_cast<const s16x8*>(wk + (slot + 16) * 32 + chunk * 8);

        // ---- counts + first two entries for all 4 tiles (conflict-free LDS) ----
        int myc[4]; unsigned int e0[4], e1[4];
#pragma unroll
        for (int j = 0; j < 4; ++j) {
            const int li = (wv * 4 + j) * 16 + slot;
            const int c = lcnt[li];
            myc[j] = c > CAPL ? CAPL : c;
            e0[j] = lists[li * LSTRIDE];        // stale-safe: gathers are masked
            e1[j] = lists[li * LSTRIDE + 1];
        }
        // ---- issue up to 8 independent gathers (depth 2 x 4 tiles) ----
        s16x8 g0[4], g1[4];
#pragma unroll
        for (int j = 0; j < 4; ++j) {
            g0[j] = (s16x8){0, 0, 0, 0, 0, 0, 0, 0};
            g1[j] = (s16x8){0, 0, 0, 0, 0, 0, 0, 0};
        }
#pragma unroll
        for (int j = 0; j < 4; ++j)
            if (0 < myc[j])
                g0[j] = *reinterpret_cast<const s16x8*>(
                    feats16 + (size_t)e0[j] * C_IN + chunk * 8);
#pragma unroll
        for (int j = 0; j < 4; ++j)
            if (1 < myc[j])
                g1[j] = *reinterpret_cast<const s16x8*>(
                    feats16 + (size_t)e1[j] * C_IN + chunk * 8);

        // ---- unpack + residual + MFMA per tile ----
#pragma unroll
        for (int j = 0; j < 4; ++j) {
            float2 af[4];
#pragma unroll
            for (int d = 0; d < 4; ++d) af[d] = make_float2(0.f, 0.f);
            unpack_add(af, g0[j]);
            unpack_add(af, g1[j]);
            const int li = (wv * 4 + j) * 16 + slot;
#pragma unroll 1
            for (int i = 2; __any(i < myc[j]); ++i) {     // rare tail
                s16x8 f = {0, 0, 0, 0, 0, 0, 0, 0};
                if (i < myc[j])
                    f = *reinterpret_cast<const s16x8*>(
                        feats16 + (size_t)lists[li * LSTRIDE + i] * C_IN + chunk * 8);
                unpack_add(af, f);
            }
            union { unsigned int w[4]; s16x8 v; } A;
#pragma unroll
            for (int d = 0; d < 4; ++d) A.w[d] = cvtpk(af[d].x, af[d].y);
            a0[j] = __builtin_amdgcn_mfma_f32_16x16x32_bf16(A.v, b0, a0[j], 0, 0, 0);
            a1[j] = __builtin_amdgcn_mfma_f32_16x16x32_bf16(A.v, b1, a1[j], 0, 0, 0);
        }
        __syncthreads();
    }

    // D layout: col = lane&15, row = chunk*4 + jj
#pragma unroll
    for (int j = 0; j < 4; ++j) {
        const int rtg = g * 32 + wv * 4 + j;
        if (rtg < NT) {
            const int r0 = rtg * 16 + chunk * 4;
#pragma unroll
            for (int jj = 0; jj < 4; ++jj) {
                out[(size_t)(r0 + jj) * C_OUT + slot]      = a0[j][jj];
                out[(size_t)(r0 + jj) * C_OUT + 16 + slot] = a1[j][jj];
            }
        }
    }
}

// ---------------- Fallback (edge-atomic) if ws too small ----------------
__global__ __launch_bounds__(256) void spconv_edges(
    const float* __restrict__ feats, const float* __restrict__ weight,
    const int* __restrict__ in_idx, const int* __restrict__ out_idx,
    float* __restrict__ out)
{
    const int k = blockIdx.y;
    const int tid = threadIdx.x;
    const int g = tid >> 3, l = tid & 7, c0 = l * 4;
    const float* wk = weight + k * (C_IN * C_OUT);
    float4 wr[32];
#pragma unroll
    for (int ci = 0; ci < 32; ++ci)
        wr[ci] = *reinterpret_cast<const float4*>(wk + ci * C_OUT + c0);
    const int* ik = in_idx + k * M_EDGE;
    const int* ok = out_idx + k * M_EDGE;
    int m = blockIdx.x * 1024 + g;
#pragma unroll 1
    for (int it = 0; it < 32; ++it, m += 32) {
        if (m >= M_EDGE) break;
        const int irow = ik[m], orow = ok[m];
        const float4* frow =
            reinterpret_cast<const float4*>(feats + (size_t)irow * C_IN);
        float4 a = make_float4(0.f, 0.f, 0.f, 0.f);
#pragma unroll
        for (int j = 0; j < 8; ++j) {
            const float4 f4 = frow[j];
            const float fv[4] = {f4.x, f4.y, f4.z, f4.w};
#pragma unroll
            for (int t = 0; t < 4; ++t) {
                const float4 w4 = wr[j * 4 + t];
                a.x = fmaf(fv[t], w4.x, a.x);
                a.y = fmaf(fv[t], w4.y, a.y);
                a.z = fmaf(fv[t], w4.z, a.z);
                a.w = fmaf(fv[t], w4.w, a.w);
            }
        }
        float* op = out + (size_t)orow * C_OUT + c0;
        unsafeAtomicAdd(op + 0, a.x);
        unsafeAtomicAdd(op + 1, a.y);
        unsafeAtomicAdd(op + 2, a.z);
        unsafeAtomicAdd(op + 3, a.w);
    }
}

extern "C" void kernel_launch(void* const* d_in, const int* in_sizes, int n_in,
                              void* d_out, int out_size, void* d_ws, size_t ws_size,
                              hipStream_t stream) {
    const float* feats   = (const float*)d_in[0];
    const float* weight  = (const float*)d_in[1];
    const int*   in_idx  = (const int*)d_in[2];
    const int*   out_idx = (const int*)d_in[3];
    float*       out     = (float*)d_out;

    const size_t feats16_elems = (size_t)N_ROWS * C_IN;          // 16M ushort
    const size_t wT16_elems    = (size_t)K_VOL * C_IN * C_OUT;   // 27,648
    const size_t need_bytes = feats16_elems * 2 + wT16_elems * 2 +
        ((size_t)NBINS_A + (NBINS_A + 1) + 1024 + E_TOT) * sizeof(int) + 256;

    if (ws_size >= need_bytes) {
        unsigned short* feats16 = (unsigned short*)d_ws;
        unsigned short* wT16    = feats16 + feats16_elems;
        int* counts = (int*)(wT16 + wT16_elems);              // NBINS_A
        int* offsA  = counts + NBINS_A;                       // NBINS_A + 1
        int* bsum   = offsA + NBINS_A + 1;                    // 1024
        unsigned int* edge_buf = (unsigned int*)(bsum + 1024);// E_TOT

        cvt_feats<<<(N_ROWS * C_IN / 8 + 255) / 256, 256, 0, stream>>>(feats, feats16);
        cvt_w<<<(K_VOL * C_IN * C_OUT + 255) / 256, 256, 0, stream>>>(weight, wT16);

        dim3 gKB(BPB, K_VOL);
        bhist_kernel<<<gKB, 256, 0, stream>>>(out_idx, counts);
        scan1_kernel<<<NSCAN_BLK, 1024, 0, stream>>>(counts, offsA, bsum);
        scan2_kernel<<<1, 1024, 0, stream>>>(bsum);
        scan3_kernel<<<NSCAN_BLK, 1024, 0, stream>>>(offsA, bsum);
        fill2_kernel<<<gKB, 256, 0, stream>>>(in_idx, out_idx, offsA, edge_buf);
        conv_mfma6<<<NREG, 512, 0, stream>>>(feats16, wT16, offsA, edge_buf, out);
    } else {
        hipMemsetAsync(out, 0, (size_t)out_size * sizeof(float), stream);
        dim3 grid((M_EDGE + 1023) / 1024, K_VOL);
        spconv_edges<<<grid, dim3(256), 0, stream>>>(feats, weight, in_idx, out_idx, out);
    }
}